// Round 1
// baseline (2381.010 us; speedup 1.0000x reference)
//
#include <hip/hip_runtime.h>
#include <hip/hip_bf16.h>
#include <math.h>

#define B 512
#define N 50
#define D 768
#define G4 3072
#define BN (B*N)        // 25600
#define FLAT (N*D)      // 38400
#define KC 1536         // fcross K (vsum|asum concat)
#define CCH 6400        // floats per egce chunk = 128 channels x 50

typedef __hip_bfloat16 bf16;
typedef short short8 __attribute__((ext_vector_type(8)));
typedef float floatx4 __attribute__((ext_vector_type(4)));

__device__ __forceinline__ float sigf(float x){ return 1.0f/(1.0f+expf(-x)); }
__device__ __forceinline__ float u2f(unsigned short u){ return __uint_as_float(((unsigned int)u)<<16); }
__device__ __forceinline__ unsigned short f2u(float f){ bf16 h=__float2bfloat16(f); return *(unsigned short*)&h; }

// ---- EGCE fused: coalesced chunked GAP + gates + gated v/a sums (one block/batch) --
__global__ __launch_bounds__(256) void egce_fused(
    const float* __restrict__ text, const int* __restrict__ vid, const int* __restrict__ aid,
    const float* __restrict__ vemb, const float* __restrict__ aemb, const float* __restrict__ egw,
    float* __restrict__ att_t, unsigned short* __restrict__ catAB){
  __shared__ float buf[CCH];
  __shared__ float gt[D+2], gv[D+2], ga[D+2];
  __shared__ float attvS[D], attaS[D];
  __shared__ int vidS[N], aidS[N];
  int b=blockIdx.x, tid=threadIdx.x;
  if(tid<N){ vidS[tid]=vid[b*N+tid]; aidS[tid]=aid[b*N+tid]; }
  if(tid==0){ gt[0]=gv[0]=ga[0]=0.f; gt[D+1]=gv[D+1]=ga[D+1]=0.f; }
  __syncthreads();
  const float* tb = text + (size_t)b*FLAT;
  for(int c=0;c<6;c++){
    int j0=c*CCH;
    for(int it=0;it<25;it++) buf[it*256+tid]=tb[j0+it*256+tid];
    __syncthreads();
    if(tid<128){ float s=0.f; for(int p=0;p<50;p++) s+=buf[tid*50+p]; gt[c*128+tid+1]=s*(1.f/50.f); }
    __syncthreads();
    for(int it=0;it<25;it++){ int j=j0+it*256+tid; int n=j/D, d=j-n*D;
      float v=vemb[vidS[n]*D+d]; buf[it*256+tid]=v>0.f?v:0.f; }
    __syncthreads();
    if(tid<128){ float s=0.f; for(int p=0;p<50;p++) s+=buf[tid*50+p]; gv[c*128+tid+1]=s*(1.f/50.f); }
    __syncthreads();
    for(int it=0;it<25;it++){ int j=j0+it*256+tid; int n=j/D, d=j-n*D;
      buf[it*256+tid]=aemb[aidS[n]*D+d]; }
    __syncthreads();
    if(tid<128){ float s=0.f; for(int p=0;p<50;p++) s+=buf[tid*50+p]; ga[c*128+tid+1]=s*(1.f/50.f); }
    __syncthreads();
  }
  float w0=egw[0],w1=egw[1],w2=egw[2];
  for(int ch=tid;ch<D;ch+=256){
    att_t[(size_t)b*D+ch]=sigf(w0*gt[ch]+w1*gt[ch+1]+w2*gt[ch+2]);
    attvS[ch]=sigf(w0*gv[ch]+w1*gv[ch+1]+w2*gv[ch+2]);
    attaS[ch]=sigf(w0*ga[ch]+w1*ga[ch+1]+w2*ga[ch+2]);
  }
  __syncthreads();
  float va[3]={0,0,0}, aa[3]={0,0,0};
  for(int n=0;n<N;n++){
    int idv=vidS[n], ida=aidS[n];
    #pragma unroll
    for(int q=0;q<3;q++){
      int d=q*256+tid;
      int ch=(n*D+d)/50;
      float vv=vemb[idv*D+d]; vv=vv>0.f?vv:0.f;
      va[q]+=vv*attvS[ch];
      aa[q]+=aemb[ida*D+d]*attaS[ch];
    }
  }
  for(int q=0;q<3;q++){
    int d=q*256+tid;
    catAB[(size_t)b*KC+d]    =f2u(va[q]);
    catAB[(size_t)b*KC+D+d]  =f2u(aa[q]);
  }
}

// ---- weight prep: LSTM gate-interleave n'=dg*4+g (bf16) + bias sums ----------------
__global__ __launch_bounds__(256) void prep_weights(
    const float* __restrict__ Wih, const float* __restrict__ Whh,
    const float* __restrict__ bih, const float* __restrict__ bhh,
    unsigned short* __restrict__ WihP, unsigned short* __restrict__ WhhP,
    float* __restrict__ bsum){
  int np = blockIdx.x;
  int dg = np>>2, g = np&3;
  size_t src = (size_t)(g*D+dg)*D;
  for(int k=threadIdx.x;k<D;k+=256){
    WihP[(size_t)np*D+k] = f2u(Wih[src+k]);
    WhhP[(size_t)np*D+k] = f2u(Whh[src+k]);
  }
  if(threadIdx.x==0) bsum[np] = bih[g*D+dg] + bhh[g*D+dg];
}

// ---- fcross weight prep ------------------------------------------------------------
__global__ __launch_bounds__(256) void prep_fcross(
    const float* __restrict__ vW, const float* __restrict__ vb,
    unsigned short* __restrict__ WcB, float* __restrict__ fb){
  int n = blockIdx.x;
  const float* W0 = vW; const float* W1 = vW + D*D; const float* W2 = vW + 2*D*D;
  for(int k=threadIdx.x;k<D;k+=256){
    WcB[(size_t)n*KC + k]     = f2u(W0[(size_t)n*D+k]);
    WcB[(size_t)n*KC + D + k] = f2u(W1[(size_t)n*D+k] + W2[(size_t)n*D+k]);
  }
  if(threadIdx.x==0) fb[n] = 50.f*(vb[n]+vb[D+n]+vb[2*D+n]);
}

// ---- fcross MFMA -------------------------------------------------------------------
__global__ __launch_bounds__(256) void fcross_mfma(
    const unsigned short* __restrict__ catAB, const unsigned short* __restrict__ WcB,
    const float* __restrict__ fb, float* __restrict__ fcross){
  __shared__ unsigned short Ash[32*40];
  __shared__ unsigned short Bsh[64*40];
  int tid=threadIdx.x;
  int bx=blockIdx.x, by=blockIdx.y;
  int lane=tid&63, w=tid>>6;
  int l15=lane&15, lq=lane>>4;
  int arow=tid>>3, aseg=(tid&7)*4;
  int brow=tid>>2, bseg=(tid&3)*8;
  floatx4 acc0={},acc1={};
  const unsigned short* aG = catAB + (size_t)(by*32 + arow)*KC + aseg;
  const unsigned short* bG = WcB   + (size_t)(bx*64 + brow)*KC + bseg;
  for(int k0=0;k0<KC;k0+=32){
    *(uint2*)&Ash[arow*40 + aseg] = *(const uint2*)(aG + k0);
    *(uint4*)&Bsh[brow*40 + bseg] = *(const uint4*)(bG + k0);
    __syncthreads();
    short8 a0=*(const short8*)&Ash[l15*40 + lq*8];
    short8 a1=*(const short8*)&Ash[(16+l15)*40 + lq*8];
    short8 bb=*(const short8*)&Bsh[(w*16 + l15)*40 + lq*8];
    acc0=__builtin_amdgcn_mfma_f32_16x16x32_bf16(a0,bb,acc0,0,0,0);
    acc1=__builtin_amdgcn_mfma_f32_16x16x32_bf16(a1,bb,acc1,0,0,0);
    __syncthreads();
  }
  int n = bx*64 + w*16 + l15;
  float bias = fb[n];
  #pragma unroll
  for(int r=0;r<4;r++){
    int m0 = by*32 + lq*4 + r;
    fcross[(size_t)m0*D + n]      = (acc0[r] + bias)*(1.f/3.f);
    fcross[(size_t)(m0+16)*D + n] = (acc1[r] + bias)*(1.f/3.f);
  }
}

// ---- fused pre-LN + LayerNorm ------------------------------------------------------
__global__ __launch_bounds__(256) void fuse_ln(
    const float* __restrict__ text, const float* __restrict__ att_t,
    const float* __restrict__ fcross, const float* __restrict__ lng,
    const float* __restrict__ lnb, bf16* __restrict__ shift){
  int row = blockIdx.x;
  int b = row/N, n = row - b*N;
  int tid=threadIdx.x;
  float v[3];
  for(int q=0;q<3;q++){
    int d=q*256+tid;
    int ch=(n*D+d)/50;
    v[q] = text[(size_t)row*D+d]*att_t[(size_t)b*D+ch] + fcross[(size_t)b*D+d];
  }
  __shared__ float red[256];
  red[tid]=v[0]+v[1]+v[2]; __syncthreads();
  for(int st=128;st>0;st>>=1){ if(tid<st) red[tid]+=red[tid+st]; __syncthreads(); }
  float m = red[0]*(1.f/768.f);
  __syncthreads();
  float s2=0.f;
  for(int q=0;q<3;q++){ float dl=v[q]-m; s2+=dl*dl; }
  red[tid]=s2; __syncthreads();
  for(int st=128;st>0;st>>=1){ if(tid<st) red[tid]+=red[tid+st]; __syncthreads(); }
  float var = red[0]*(1.f/768.f);
  float rs = 1.f/sqrtf(var+1e-5f);
  for(int q=0;q<3;q++){
    int d=q*256+tid;
    shift[(size_t)row*D+d]=__float2bfloat16((v[q]-m)*rs*lng[d]+lnb[d]);
  }
}

// ---------------- barrier flag init -------------------------------------------------
__global__ __launch_bounds__(256) void zero_bar(int* __restrict__ bar){
  bar[threadIdx.x] = 0;
}

// ---- persistent fused LSTM: all 50 steps, xg fused (gates = h@Whh^T + x@Wih^T + b) -
// Grid 256 blocks x 512 thr. Block tile: 64 m (batch) x 96 n' (gate cols).
// XCD-bijective map: each XCD gets 4 W-panels x all 8 m-tiles for L2 merge.
// Operand-swapped MFMA: D[n',m] -> each thread holds i,f,g,o of one dg in acc[fi][0..3];
// c-state in registers across all 50 steps. One barrier per K-step (dbuf W slices).
__global__ __launch_bounds__(512) void lstm_persist(
    const unsigned short* __restrict__ shift, const unsigned short* __restrict__ WihP,
    const unsigned short* __restrict__ WhhP, const float* __restrict__ bsum,
    const float* __restrict__ text, const float* __restrict__ att_t,
    unsigned short* __restrict__ h0b, unsigned short* __restrict__ h1b,
    float* __restrict__ out, int* __restrict__ bar){
  __shared__ unsigned short Wsl[2*2*3840];   // [buf][whh|wih][96 rows x 40 (32k pad8)] = 30 KB
  const int tid = threadIdx.x;
  const int bid = blockIdx.x;
  const int k8 = bid & 7, u = bid >> 3;
  const int gy = u & 7;                      // m-tile (64 rows)
  const int gx = (u >> 3) + (k8 << 2);       // n'-panel (96 cols), 4 panels per XCD
  const int lane = tid & 63, w = tid >> 6;
  const int wn = w & 1, wm = w >> 1;         // wave tile: 48 n' x 16 m
  const int l15 = lane & 15, lq = lane >> 4;

  // ---- staging slot map: 768 16B-slots (384 whh + 384 wih); tid<256 takes a 2nd ----
  const int arrA = (tid < 384) ? 0 : 1;
  const int sA   = (tid < 384) ? tid : tid - 384;
  const int rlA = sA >> 2, cA = sA & 3;
  const unsigned short* srcA = (arrA ? WihP : WhhP) + (size_t)(gx*96 + rlA)*D + cA*8;
  const int dA = arrA*3840 + rlA*40 + cA*8;
  const bool hasB = (tid < 256);
  const int sB = tid + 128;                  // wih slot
  const int rlB = sB >> 2, cB = sB & 3;
  const unsigned short* srcB = WihP + (size_t)(gx*96 + rlB)*D + cB*8;
  const int dB = 3840 + rlB*40 + cB*8;

  const int mrow = gy*64 + wm*16 + l15;      // this lane's batch row (B-frag col)
  int rdh[3], rdi[3];
  #pragma unroll
  for(int fi=0;fi<3;fi++){
    int rl = wn*48 + fi*16 + l15;
    rdh[fi] = rl*40 + lq*8;
    rdi[fi] = 3840 + rl*40 + lq*8;
  }
  int dgv[3]; floatx4 bs[3];
  #pragma unroll
  for(int fi=0;fi<3;fi++){
    int nb = gx*96 + wn*48 + fi*16 + lq*4;
    dgv[fi] = nb >> 2;
    bs[fi] = *(const floatx4*)&bsum[nb];
  }

  float cst[3] = {0.f, 0.f, 0.f};            // c-state, register-resident all 50 steps

  #pragma unroll 1
  for(int t=0;t<50;++t){
    const unsigned short* hR = (t&1) ? h1b : h0b;
    unsigned short* hW = (t&1) ? h0b : h1b;
    const unsigned short* sP = shift + ((size_t)mrow*N + t)*D + lq*8;
    const unsigned short* hP = hR + (size_t)mrow*D + lq*8;

    floatx4 acc[3] = {};

    // prologue: stage k0=0, prefetch first h/shift frags
    uint4 rA = *(const uint4*)(srcA);
    uint4 rB = {}; if(hasB) rB = *(const uint4*)(srcB);
    short8 sfC = *(const short8*)(sP);
    short8 hfC = {}; if(t) hfC = *(const short8*)(hP);
    *(uint4*)&Wsl[dA] = rA;
    if(hasB) *(uint4*)&Wsl[dB] = rB;
    __syncthreads();

    #pragma unroll
    for(int kk=0;kk<24;++kk){
      const int bo = (kk&1)*7680;
      uint4 nA = {}; uint4 nB = {}; short8 sfN = {}; short8 hfN = {};
      if(kk < 23){
        nA = *(const uint4*)(srcA + (kk+1)*32);
        if(hasB) nB = *(const uint4*)(srcB + (kk+1)*32);
        sfN = *(const short8*)(sP + (kk+1)*32);
        if(t) hfN = *(const short8*)(hP + (kk+1)*32);
      }
      #pragma unroll
      for(int fi=0;fi<3;fi++){
        short8 wi = *(const short8*)&Wsl[bo + rdi[fi]];
        acc[fi] = __builtin_amdgcn_mfma_f32_16x16x32_bf16(wi, sfC, acc[fi], 0,0,0);
      }
      if(t){
        #pragma unroll
        for(int fi=0;fi<3;fi++){
          short8 wh = *(const short8*)&Wsl[bo + rdh[fi]];
          acc[fi] = __builtin_amdgcn_mfma_f32_16x16x32_bf16(wh, hfC, acc[fi], 0,0,0);
        }
      }
      if(kk < 23){
        const int nx = 7680 - bo;
        *(uint4*)&Wsl[nx + dA] = nA;
        if(hasB) *(uint4*)&Wsl[nx + dB] = nB;
        sfC = sfN; hfC = hfN;
      }
      __syncthreads();
    }

    // ---- epilogue: gates -> c,h (c in regs); write h + fused residual out ----------
    size_t tb = ((size_t)mrow*N + t)*D;
    #pragma unroll
    for(int fi=0;fi<3;fi++){
      float gi = acc[fi][0] + bs[fi][0];
      float gf = acc[fi][1] + bs[fi][1];
      float gg = acc[fi][2] + bs[fi][2];
      float go = acc[fi][3] + bs[fi][3];
      float cn = sigf(gf)*cst[fi] + sigf(gi)*tanhf(gg);
      float hn = sigf(go)*tanhf(cn);
      cst[fi] = cn;
      int dg = dgv[fi];
      hW[(size_t)mrow*D + dg] = f2u(hn);
      int ch = (t*D + dg)/50;
      out[tb + dg] = hn + text[tb + dg]*att_t[(size_t)mrow*D + ch];
    }

    // ---- grid barrier (flag array, no contended atomics) ---------------------------
    if(t < 49){
      __syncthreads();                        // all waves' stores drained to L2
      if(tid == 0){
        __threadfence();                      // write back XCD L2 -> device-visible
        __hip_atomic_store(&bar[bid], t+1, __ATOMIC_RELEASE, __HIP_MEMORY_SCOPE_AGENT);
      }
      if(w == 0){                             // wave 0 polls all 256 arrival flags
        int i0 = lane*4;
        while(true){
          int a0 = __hip_atomic_load(&bar[i0+0], __ATOMIC_RELAXED, __HIP_MEMORY_SCOPE_AGENT);
          int a1 = __hip_atomic_load(&bar[i0+1], __ATOMIC_RELAXED, __HIP_MEMORY_SCOPE_AGENT);
          int a2 = __hip_atomic_load(&bar[i0+2], __ATOMIC_RELAXED, __HIP_MEMORY_SCOPE_AGENT);
          int a3 = __hip_atomic_load(&bar[i0+3], __ATOMIC_RELAXED, __HIP_MEMORY_SCOPE_AGENT);
          int mn = min(min(a0,a1), min(a2,a3));
          if(__all(mn >= t+1)) break;
          __builtin_amdgcn_s_sleep(2);
        }
        __threadfence();                      // invalidate L1/L2 before next-step reads
      }
      __syncthreads();
    }
  }
}

extern "C" void kernel_launch(void* const* d_in, const int* in_sizes, int n_in,
                              void* d_out, int out_size, void* d_ws, size_t ws_size,
                              hipStream_t stream){
  const float* text=(const float*)d_in[0];
  const int*  vid =(const int*) d_in[1];
  const int*  aid =(const int*) d_in[2];
  const float* vemb=(const float*)d_in[3];
  const float* aemb=(const float*)d_in[4];
  const float* egw =(const float*)d_in[5];
  const float* Wih =(const float*)d_in[6];
  const float* Whh =(const float*)d_in[7];
  const float* bih =(const float*)d_in[8];
  const float* bhh =(const float*)d_in[9];
  const float* lng =(const float*)d_in[10];
  const float* lnb =(const float*)d_in[11];
  const float* vW  =(const float*)d_in[20];
  const float* vb  =(const float*)d_in[21];
  float* out = (float*)d_out;

  // ---- workspace layout (identical to proven-safe layout; cbuf region -> barrier) --
  float* W = (float*)d_ws;
  const size_t S = (size_t)B*D;
  float* att_t = W;
  float* fcross= att_t + S;
  float* cbuf  = fcross + S;             // reused as barrier flag array (256 ints)
  float* bsum  = cbuf + S;               // G4
  float* fb    = bsum + G4;              // D
  unsigned short* WihP = (unsigned short*)(fb + D);      // G4*D
  unsigned short* WhhP = WihP + (size_t)G4*D;            // G4*D
  unsigned short* WcB  = WhhP + (size_t)G4*D;            // D*KC
  unsigned short* catAB= WcB + (size_t)D*KC;             // B*KC
  unsigned short* hA0  = catAB + (size_t)B*KC;           // S
  unsigned short* hA1  = hA0 + S;                        // S
  bf16*  shift = (bf16*)(hA1 + S);                       // BN*D
  int* bar = (int*)cbuf;

  prep_weights<<<G4,256,0,stream>>>(Wih,Whh,bih,bhh,WihP,WhhP,bsum);
  prep_fcross<<<D,256,0,stream>>>(vW,vb,WcB,fb);
  egce_fused<<<B,256,0,stream>>>(text,vid,aid,vemb,aemb,egw,att_t,catAB);
  fcross_mfma<<<dim3(12,16),256,0,stream>>>(catAB,WcB,fb,fcross);
  fuse_ln<<<BN,256,0,stream>>>(text,att_t,fcross,lng,lnb,shift);
  zero_bar<<<1,256,0,stream>>>(bar);
  lstm_persist<<<256,512,0,stream>>>((const unsigned short*)shift,WihP,WhhP,bsum,
                                     text,att_t,hA0,hA1,out,bar);
}

// Round 2
// 1267.588 us; speedup vs baseline: 1.8784x; 1.8784x over previous
//
#include <hip/hip_runtime.h>
#include <hip/hip_bf16.h>
#include <math.h>

#define B 512
#define N 50
#define D 768
#define G4 3072
#define KCAT 1536       // concat K for fused step GEMM: [Whh | Wih]
#define BN (B*N)        // 25600
#define FLAT (N*D)      // 38400
#define KC 1536         // fcross K (vsum|asum concat)
#define CCH 6400        // floats per egce chunk = 128 channels x 50

typedef __hip_bfloat16 bf16;
typedef short short8 __attribute__((ext_vector_type(8)));
typedef float floatx4 __attribute__((ext_vector_type(4)));

__device__ __forceinline__ float sigf(float x){ return 1.0f/(1.0f+expf(-x)); }
__device__ __forceinline__ float u2f(unsigned short u){ return __uint_as_float(((unsigned int)u)<<16); }
__device__ __forceinline__ unsigned short f2u(float f){ bf16 h=__float2bfloat16(f); return *(unsigned short*)&h; }

// ---- EGCE fused: coalesced chunked GAP + gates + gated v/a sums (one block/batch) --
__global__ __launch_bounds__(256) void egce_fused(
    const float* __restrict__ text, const int* __restrict__ vid, const int* __restrict__ aid,
    const float* __restrict__ vemb, const float* __restrict__ aemb, const float* __restrict__ egw,
    float* __restrict__ att_t, unsigned short* __restrict__ catAB){
  __shared__ float buf[CCH];
  __shared__ float gt[D+2], gv[D+2], ga[D+2];
  __shared__ float attvS[D], attaS[D];
  __shared__ int vidS[N], aidS[N];
  int b=blockIdx.x, tid=threadIdx.x;
  if(tid<N){ vidS[tid]=vid[b*N+tid]; aidS[tid]=aid[b*N+tid]; }
  if(tid==0){ gt[0]=gv[0]=ga[0]=0.f; gt[D+1]=gv[D+1]=ga[D+1]=0.f; }
  __syncthreads();
  const float* tb = text + (size_t)b*FLAT;
  for(int c=0;c<6;c++){
    int j0=c*CCH;
    for(int it=0;it<25;it++) buf[it*256+tid]=tb[j0+it*256+tid];
    __syncthreads();
    if(tid<128){ float s=0.f; for(int p=0;p<50;p++) s+=buf[tid*50+p]; gt[c*128+tid+1]=s*(1.f/50.f); }
    __syncthreads();
    for(int it=0;it<25;it++){ int j=j0+it*256+tid; int n=j/D, d=j-n*D;
      float v=vemb[vidS[n]*D+d]; buf[it*256+tid]=v>0.f?v:0.f; }
    __syncthreads();
    if(tid<128){ float s=0.f; for(int p=0;p<50;p++) s+=buf[tid*50+p]; gv[c*128+tid+1]=s*(1.f/50.f); }
    __syncthreads();
    for(int it=0;it<25;it++){ int j=j0+it*256+tid; int n=j/D, d=j-n*D;
      buf[it*256+tid]=aemb[aidS[n]*D+d]; }
    __syncthreads();
    if(tid<128){ float s=0.f; for(int p=0;p<50;p++) s+=buf[tid*50+p]; ga[c*128+tid+1]=s*(1.f/50.f); }
    __syncthreads();
  }
  float w0=egw[0],w1=egw[1],w2=egw[2];
  for(int ch=tid;ch<D;ch+=256){
    att_t[(size_t)b*D+ch]=sigf(w0*gt[ch]+w1*gt[ch+1]+w2*gt[ch+2]);
    attvS[ch]=sigf(w0*gv[ch]+w1*gv[ch+1]+w2*gv[ch+2]);
    attaS[ch]=sigf(w0*ga[ch]+w1*ga[ch+1]+w2*ga[ch+2]);
  }
  __syncthreads();
  float va[3]={0,0,0}, aa[3]={0,0,0};
  for(int n=0;n<N;n++){
    int idv=vidS[n], ida=aidS[n];
    #pragma unroll
    for(int q=0;q<3;q++){
      int d=q*256+tid;
      int ch=(n*D+d)/50;
      float vv=vemb[idv*D+d]; vv=vv>0.f?vv:0.f;
      va[q]+=vv*attvS[ch];
      aa[q]+=aemb[ida*D+d]*attaS[ch];
    }
  }
  for(int q=0;q<3;q++){
    int d=q*256+tid;
    catAB[(size_t)b*KC+d]    =f2u(va[q]);
    catAB[(size_t)b*KC+D+d]  =f2u(aa[q]);
  }
}

// ---- weight prep: concat [Whh | Wih] rows, gate-interleave n'=dg*4+g (bf16) --------
__global__ __launch_bounds__(256) void prep_weights(
    const float* __restrict__ Wih, const float* __restrict__ Whh,
    const float* __restrict__ bih, const float* __restrict__ bhh,
    unsigned short* __restrict__ Wcat, float* __restrict__ bsum){
  int np = blockIdx.x;
  int dg = np>>2, g = np&3;
  size_t src = (size_t)(g*D+dg)*D;
  for(int k=threadIdx.x;k<D;k+=256){
    Wcat[(size_t)np*KCAT + k]     = f2u(Whh[src+k]);
    Wcat[(size_t)np*KCAT + D + k] = f2u(Wih[src+k]);
  }
  if(threadIdx.x==0) bsum[np] = bih[g*D+dg] + bhh[g*D+dg];
}

// ---- fcross weight prep ------------------------------------------------------------
__global__ __launch_bounds__(256) void prep_fcross(
    const float* __restrict__ vW, const float* __restrict__ vb,
    unsigned short* __restrict__ WcB, float* __restrict__ fb){
  int n = blockIdx.x;
  const float* W0 = vW; const float* W1 = vW + D*D; const float* W2 = vW + 2*D*D;
  for(int k=threadIdx.x;k<D;k+=256){
    WcB[(size_t)n*KC + k]     = f2u(W0[(size_t)n*D+k]);
    WcB[(size_t)n*KC + D + k] = f2u(W1[(size_t)n*D+k] + W2[(size_t)n*D+k]);
  }
  if(threadIdx.x==0) fb[n] = 50.f*(vb[n]+vb[D+n]+vb[2*D+n]);
}

// ---- fcross MFMA -------------------------------------------------------------------
__global__ __launch_bounds__(256) void fcross_mfma(
    const unsigned short* __restrict__ catAB, const unsigned short* __restrict__ WcB,
    const float* __restrict__ fb, float* __restrict__ fcross){
  __shared__ unsigned short Ash[32*40];
  __shared__ unsigned short Bsh[64*40];
  int tid=threadIdx.x;
  int bx=blockIdx.x, by=blockIdx.y;
  int lane=tid&63, w=tid>>6;
  int l15=lane&15, lq=lane>>4;
  int arow=tid>>3, aseg=(tid&7)*4;
  int brow=tid>>2, bseg=(tid&3)*8;
  floatx4 acc0={},acc1={};
  const unsigned short* aG = catAB + (size_t)(by*32 + arow)*KC + aseg;
  const unsigned short* bG = WcB   + (size_t)(bx*64 + brow)*KC + bseg;
  for(int k0=0;k0<KC;k0+=32){
    *(uint2*)&Ash[arow*40 + aseg] = *(const uint2*)(aG + k0);
    *(uint4*)&Bsh[brow*40 + bseg] = *(const uint4*)(bG + k0);
    __syncthreads();
    short8 a0=*(const short8*)&Ash[l15*40 + lq*8];
    short8 a1=*(const short8*)&Ash[(16+l15)*40 + lq*8];
    short8 bb=*(const short8*)&Bsh[(w*16 + l15)*40 + lq*8];
    acc0=__builtin_amdgcn_mfma_f32_16x16x32_bf16(a0,bb,acc0,0,0,0);
    acc1=__builtin_amdgcn_mfma_f32_16x16x32_bf16(a1,bb,acc1,0,0,0);
    __syncthreads();
  }
  int n = bx*64 + w*16 + l15;
  float bias = fb[n];
  #pragma unroll
  for(int r=0;r<4;r++){
    int m0 = by*32 + lq*4 + r;
    fcross[(size_t)m0*D + n]      = (acc0[r] + bias)*(1.f/3.f);
    fcross[(size_t)(m0+16)*D + n] = (acc1[r] + bias)*(1.f/3.f);
  }
}

// ---- fused pre-LN + LayerNorm ------------------------------------------------------
__global__ __launch_bounds__(256) void fuse_ln(
    const float* __restrict__ text, const float* __restrict__ att_t,
    const float* __restrict__ fcross, const float* __restrict__ lng,
    const float* __restrict__ lnb, bf16* __restrict__ shift){
  int row = blockIdx.x;
  int b = row/N, n = row - b*N;
  int tid=threadIdx.x;
  float v[3];
  for(int q=0;q<3;q++){
    int d=q*256+tid;
    int ch=(n*D+d)/50;
    v[q] = text[(size_t)row*D+d]*att_t[(size_t)b*D+ch] + fcross[(size_t)b*D+d];
  }
  __shared__ float red[256];
  red[tid]=v[0]+v[1]+v[2]; __syncthreads();
  for(int st=128;st>0;st>>=1){ if(tid<st) red[tid]+=red[tid+st]; __syncthreads(); }
  float m = red[0]*(1.f/768.f);
  __syncthreads();
  float s2=0.f;
  for(int q=0;q<3;q++){ float dl=v[q]-m; s2+=dl*dl; }
  red[tid]=s2; __syncthreads();
  for(int st=128;st>0;st>>=1){ if(tid<st) red[tid]+=red[tid+st]; __syncthreads(); }
  float var = red[0]*(1.f/768.f);
  float rs = 1.f/sqrtf(var+1e-5f);
  for(int q=0;q<3;q++){
    int d=q*256+tid;
    shift[(size_t)row*D+d]=__float2bfloat16((v[q]-m)*rs*lng[d]+lnb[d]);
  }
}

// ---- fused LSTM step: gates = [h|x]@[Whh|Wih]^T + b, one launch per timestep -------
// Grid (48,16) = 768 blocks (3/CU). Tile 32 m x 64 n'. BK=64, double-buffered LDS,
// ONE barrier per K-iter. LDS layout [kh][row][40] = proven conflict-free stride-40.
// Operand-swapped MFMA (verified R1): acc[r] = gate r of one dg -> LSTM math in regs.
__global__ __launch_bounds__(256) void lstm_fused(
    const unsigned short* __restrict__ shift, const unsigned short* __restrict__ Wcat,
    const float* __restrict__ bsum, const unsigned short* __restrict__ hprev,
    unsigned short* __restrict__ hnext, float* __restrict__ cbuf,
    const float* __restrict__ text, const float* __restrict__ att_t,
    float* __restrict__ out, int t){
  __shared__ unsigned short Ab[2][64*40];    // [buf][kh*32+row][40]
  __shared__ unsigned short Bb[2][128*40];   // [buf][kh*64+row][40]
  const int tid=threadIdx.x, bx=blockIdx.x, by=blockIdx.y;
  const int lane=tid&63, w=tid>>6, l15=lane&15, lq=lane>>4;

  // ---- staging maps (uint4 = 8 shorts per slot) ----
  const int sra = tid>>2, ca=(tid&3)*8;        // A: 64 subrows x 4 segs = 256 slots
  const int arow = sra&31, ah = sra>>5;
  const int dA = sra*40 + ca;
  const int b_a = by*32 + arow;
  const unsigned short* hThr = hprev + (size_t)b_a*D + ah*32 + ca;
  const unsigned short* xThr = shift + ((size_t)b_a*N + t)*D + ah*32 + ca;

  const int sr0 = tid>>2,        c0=(tid&3)*8;       // B slot 0: subrows 0..63 (kh=0)
  const int sr1 = (tid+256)>>2,  c1=(tid&3)*8;       // B slot 1: subrows 64..127 (kh=1)
  const int br0 = sr0&63, bh0 = sr0>>6;
  const int br1 = sr1&63, bh1 = sr1>>6;
  const unsigned short* bThr0 = Wcat + (size_t)(bx*64+br0)*KCAT + bh0*32 + c0;
  const unsigned short* bThr1 = Wcat + (size_t)(bx*64+br1)*KCAT + bh1*32 + c1;
  const int dB0 = sr0*40 + c0, dB1 = sr1*40 + c1;

  const int kbase  = t ? 0 : 768;              // t=0: h is zero -> skip Whh half
  const int nIters = t ? 24 : 12;

  floatx4 acc0={}, acc1={};

  // prologue: stage iter 0 into buf 0
  {
    const unsigned short* ap = (kbase<768) ? (hThr + kbase) : (xThr + (kbase-768));
    uint4 pA  = *(const uint4*)ap;
    uint4 pB0 = *(const uint4*)(bThr0 + kbase);
    uint4 pB1 = *(const uint4*)(bThr1 + kbase);
    *(uint4*)&Ab[0][dA]  = pA;
    *(uint4*)&Bb[0][dB0] = pB0;
    *(uint4*)&Bb[0][dB1] = pB1;
  }
  __syncthreads();

  #pragma unroll 2
  for(int it=0; it<nIters; ++it){
    const int cur = it&1;
    uint4 nA, nB0, nB1;
    const bool more = (it+1 < nIters);
    if(more){
      int kg = kbase + (it+1)*64;
      const unsigned short* ap = (kg<768) ? (hThr + kg) : (xThr + (kg-768));
      nA  = *(const uint4*)ap;
      nB0 = *(const uint4*)(bThr0 + kg);
      nB1 = *(const uint4*)(bThr1 + kg);
    }
    short8 Wf0 = *(const short8*)&Bb[cur][(w*16+l15)*40 + lq*8];
    short8 Wf1 = *(const short8*)&Bb[cur][(64 + w*16+l15)*40 + lq*8];
    short8 X00 = *(const short8*)&Ab[cur][(l15)*40 + lq*8];
    short8 X10 = *(const short8*)&Ab[cur][(16+l15)*40 + lq*8];
    short8 X01 = *(const short8*)&Ab[cur][(32+l15)*40 + lq*8];
    short8 X11 = *(const short8*)&Ab[cur][(48+l15)*40 + lq*8];
    acc0 = __builtin_amdgcn_mfma_f32_16x16x32_bf16(Wf0, X00, acc0, 0,0,0);
    acc1 = __builtin_amdgcn_mfma_f32_16x16x32_bf16(Wf0, X10, acc1, 0,0,0);
    acc0 = __builtin_amdgcn_mfma_f32_16x16x32_bf16(Wf1, X01, acc0, 0,0,0);
    acc1 = __builtin_amdgcn_mfma_f32_16x16x32_bf16(Wf1, X11, acc1, 0,0,0);
    if(more){
      *(uint4*)&Ab[cur^1][dA]  = nA;
      *(uint4*)&Bb[cur^1][dB0] = nB0;
      *(uint4*)&Bb[cur^1][dB1] = nB1;
    }
    __syncthreads();
  }

  // ---- epilogue: gates -> c,h ; fused residual out-write -----------------------
  const int nb = bx*64 + w*16 + lq*4;
  const int dg = nb>>2;                        // = bx*16 + w*4 + lq
  floatx4 bs = *(const floatx4*)&bsum[nb];
  #pragma unroll
  for(int mf=0; mf<2; ++mf){
    floatx4 a = mf ? acc1 : acc0;
    int b = by*32 + mf*16 + l15;
    float gi=a[0]+bs[0], gf=a[1]+bs[1], gg=a[2]+bs[2], go=a[3]+bs[3];
    float co = t ? cbuf[(size_t)b*D+dg] : 0.f;
    float cn = sigf(gf)*co + sigf(gi)*tanhf(gg);
    float hn = sigf(go)*tanhf(cn);
    cbuf[(size_t)b*D+dg] = cn;
    hnext[(size_t)b*D+dg] = f2u(hn);
    int ch = (t*D+dg)/50;
    size_t oi = ((size_t)b*N + t)*D + dg;
    out[oi] = hn + text[oi]*att_t[(size_t)b*D+ch];
  }
}

extern "C" void kernel_launch(void* const* d_in, const int* in_sizes, int n_in,
                              void* d_out, int out_size, void* d_ws, size_t ws_size,
                              hipStream_t stream){
  const float* text=(const float*)d_in[0];
  const int*  vid =(const int*) d_in[1];
  const int*  aid =(const int*) d_in[2];
  const float* vemb=(const float*)d_in[3];
  const float* aemb=(const float*)d_in[4];
  const float* egw =(const float*)d_in[5];
  const float* Wih =(const float*)d_in[6];
  const float* Whh =(const float*)d_in[7];
  const float* bih =(const float*)d_in[8];
  const float* bhh =(const float*)d_in[9];
  const float* lng =(const float*)d_in[10];
  const float* lnb =(const float*)d_in[11];
  const float* vW  =(const float*)d_in[20];
  const float* vb  =(const float*)d_in[21];
  float* out = (float*)d_out;

  // ---- workspace layout (~60 MB, under proven-safe 91 MB) ----
  float* W = (float*)d_ws;
  const size_t S = (size_t)B*D;
  float* att_t = W;
  float* fcross= att_t + S;
  float* cbuf  = fcross + S;
  float* bsum  = cbuf + S;               // G4
  float* fb    = bsum + G4;              // D
  unsigned short* Wcat = (unsigned short*)(fb + D);      // G4*KCAT
  unsigned short* WcB  = Wcat + (size_t)G4*KCAT;         // D*KC
  unsigned short* catAB= WcB + (size_t)D*KC;             // B*KC
  unsigned short* hA0  = catAB + (size_t)B*KC;           // S
  unsigned short* hA1  = hA0 + S;                        // S
  bf16*  shift = (bf16*)(hA1 + S);                       // BN*D

  prep_weights<<<G4,256,0,stream>>>(Wih,Whh,bih,bhh,Wcat,bsum);
  prep_fcross<<<D,256,0,stream>>>(vW,vb,WcB,fb);
  egce_fused<<<B,256,0,stream>>>(text,vid,aid,vemb,aemb,egw,att_t,catAB);
  fcross_mfma<<<dim3(12,16),256,0,stream>>>(catAB,WcB,fb,fcross);
  fuse_ln<<<BN,256,0,stream>>>(text,att_t,fcross,lng,lnb,shift);

  for(int t=0;t<N;t++){
    unsigned short* hp = (t&1)? hA1 : hA0;
    unsigned short* hn = (t&1)? hA0 : hA1;
    lstm_fused<<<dim3(48,16),256,0,stream>>>((const unsigned short*)shift,Wcat,bsum,
                                             hp,hn,cbuf,text,att_t,out,t);
  }
}

// Round 3
// 1236.544 us; speedup vs baseline: 1.9255x; 1.0251x over previous
//
#include <hip/hip_runtime.h>
#include <hip/hip_bf16.h>
#include <math.h>

#define B 512
#define N 50
#define D 768
#define G4 3072
#define KCAT 1536       // concat K for fused step GEMM: [Whh | Wih]
#define BN (B*N)        // 25600
#define FLAT (N*D)      // 38400
#define KC 1536         // fcross K (vsum|asum concat)
#define CCH 6400        // floats per egce chunk = 128 channels x 50

typedef __hip_bfloat16 bf16;
typedef short short8 __attribute__((ext_vector_type(8)));
typedef float floatx4 __attribute__((ext_vector_type(4)));

__device__ __forceinline__ float sigf(float x){ return 1.0f/(1.0f+expf(-x)); }
__device__ __forceinline__ float u2f(unsigned short u){ return __uint_as_float(((unsigned int)u)<<16); }
__device__ __forceinline__ unsigned short f2u(float f){ bf16 h=__float2bfloat16(f); return *(unsigned short*)&h; }

// ---- EGCE fused: coalesced chunked GAP + gates + gated v/a sums (one block/batch) --
__global__ __launch_bounds__(256) void egce_fused(
    const float* __restrict__ text, const int* __restrict__ vid, const int* __restrict__ aid,
    const float* __restrict__ vemb, const float* __restrict__ aemb, const float* __restrict__ egw,
    float* __restrict__ att_t, unsigned short* __restrict__ catAB){
  __shared__ float buf[CCH];
  __shared__ float gt[D+2], gv[D+2], ga[D+2];
  __shared__ float attvS[D], attaS[D];
  __shared__ int vidS[N], aidS[N];
  int b=blockIdx.x, tid=threadIdx.x;
  if(tid<N){ vidS[tid]=vid[b*N+tid]; aidS[tid]=aid[b*N+tid]; }
  if(tid==0){ gt[0]=gv[0]=ga[0]=0.f; gt[D+1]=gv[D+1]=ga[D+1]=0.f; }
  __syncthreads();
  const float* tb = text + (size_t)b*FLAT;
  for(int c=0;c<6;c++){
    int j0=c*CCH;
    for(int it=0;it<25;it++) buf[it*256+tid]=tb[j0+it*256+tid];
    __syncthreads();
    if(tid<128){ float s=0.f; for(int p=0;p<50;p++) s+=buf[tid*50+p]; gt[c*128+tid+1]=s*(1.f/50.f); }
    __syncthreads();
    for(int it=0;it<25;it++){ int j=j0+it*256+tid; int n=j/D, d=j-n*D;
      float v=vemb[vidS[n]*D+d]; buf[it*256+tid]=v>0.f?v:0.f; }
    __syncthreads();
    if(tid<128){ float s=0.f; for(int p=0;p<50;p++) s+=buf[tid*50+p]; gv[c*128+tid+1]=s*(1.f/50.f); }
    __syncthreads();
    for(int it=0;it<25;it++){ int j=j0+it*256+tid; int n=j/D, d=j-n*D;
      buf[it*256+tid]=aemb[aidS[n]*D+d]; }
    __syncthreads();
    if(tid<128){ float s=0.f; for(int p=0;p<50;p++) s+=buf[tid*50+p]; ga[c*128+tid+1]=s*(1.f/50.f); }
    __syncthreads();
  }
  float w0=egw[0],w1=egw[1],w2=egw[2];
  for(int ch=tid;ch<D;ch+=256){
    att_t[(size_t)b*D+ch]=sigf(w0*gt[ch]+w1*gt[ch+1]+w2*gt[ch+2]);
    attvS[ch]=sigf(w0*gv[ch]+w1*gv[ch+1]+w2*gv[ch+2]);
    attaS[ch]=sigf(w0*ga[ch]+w1*ga[ch+1]+w2*ga[ch+2]);
  }
  __syncthreads();
  float va[3]={0,0,0}, aa[3]={0,0,0};
  for(int n=0;n<N;n++){
    int idv=vidS[n], ida=aidS[n];
    #pragma unroll
    for(int q=0;q<3;q++){
      int d=q*256+tid;
      int ch=(n*D+d)/50;
      float vv=vemb[idv*D+d]; vv=vv>0.f?vv:0.f;
      va[q]+=vv*attvS[ch];
      aa[q]+=aemb[ida*D+d]*attaS[ch];
    }
  }
  for(int q=0;q<3;q++){
    int d=q*256+tid;
    catAB[(size_t)b*KC+d]    =f2u(va[q]);
    catAB[(size_t)b*KC+D+d]  =f2u(aa[q]);
  }
}

// ---- weight prep: concat [Whh | Wih] rows, gate-interleave n'=dg*4+g (bf16) --------
__global__ __launch_bounds__(256) void prep_weights(
    const float* __restrict__ Wih, const float* __restrict__ Whh,
    const float* __restrict__ bih, const float* __restrict__ bhh,
    unsigned short* __restrict__ Wcat, float* __restrict__ bsum){
  int np = blockIdx.x;
  int dg = np>>2, g = np&3;
  size_t src = (size_t)(g*D+dg)*D;
  for(int k=threadIdx.x;k<D;k+=256){
    Wcat[(size_t)np*KCAT + k]     = f2u(Whh[src+k]);
    Wcat[(size_t)np*KCAT + D + k] = f2u(Wih[src+k]);
  }
  if(threadIdx.x==0) bsum[np] = bih[g*D+dg] + bhh[g*D+dg];
}

// ---- fcross weight prep ------------------------------------------------------------
__global__ __launch_bounds__(256) void prep_fcross(
    const float* __restrict__ vW, const float* __restrict__ vb,
    unsigned short* __restrict__ WcB, float* __restrict__ fb){
  int n = blockIdx.x;
  const float* W0 = vW; const float* W1 = vW + D*D; const float* W2 = vW + 2*D*D;
  for(int k=threadIdx.x;k<D;k+=256){
    WcB[(size_t)n*KC + k]     = f2u(W0[(size_t)n*D+k]);
    WcB[(size_t)n*KC + D + k] = f2u(W1[(size_t)n*D+k] + W2[(size_t)n*D+k]);
  }
  if(threadIdx.x==0) fb[n] = 50.f*(vb[n]+vb[D+n]+vb[2*D+n]);
}

// ---- fcross MFMA -------------------------------------------------------------------
__global__ __launch_bounds__(256) void fcross_mfma(
    const unsigned short* __restrict__ catAB, const unsigned short* __restrict__ WcB,
    const float* __restrict__ fb, float* __restrict__ fcross){
  __shared__ unsigned short Ash[32*40];
  __shared__ unsigned short Bsh[64*40];
  int tid=threadIdx.x;
  int bx=blockIdx.x, by=blockIdx.y;
  int lane=tid&63, w=tid>>6;
  int l15=lane&15, lq=lane>>4;
  int arow=tid>>3, aseg=(tid&7)*4;
  int brow=tid>>2, bseg=(tid&3)*8;
  floatx4 acc0={},acc1={};
  const unsigned short* aG = catAB + (size_t)(by*32 + arow)*KC + aseg;
  const unsigned short* bG = WcB   + (size_t)(bx*64 + brow)*KC + bseg;
  for(int k0=0;k0<KC;k0+=32){
    *(uint2*)&Ash[arow*40 + aseg] = *(const uint2*)(aG + k0);
    *(uint4*)&Bsh[brow*40 + bseg] = *(const uint4*)(bG + k0);
    __syncthreads();
    short8 a0=*(const short8*)&Ash[l15*40 + lq*8];
    short8 a1=*(const short8*)&Ash[(16+l15)*40 + lq*8];
    short8 bb=*(const short8*)&Bsh[(w*16 + l15)*40 + lq*8];
    acc0=__builtin_amdgcn_mfma_f32_16x16x32_bf16(a0,bb,acc0,0,0,0);
    acc1=__builtin_amdgcn_mfma_f32_16x16x32_bf16(a1,bb,acc1,0,0,0);
    __syncthreads();
  }
  int n = bx*64 + w*16 + l15;
  float bias = fb[n];
  #pragma unroll
  for(int r=0;r<4;r++){
    int m0 = by*32 + lq*4 + r;
    fcross[(size_t)m0*D + n]      = (acc0[r] + bias)*(1.f/3.f);
    fcross[(size_t)(m0+16)*D + n] = (acc1[r] + bias)*(1.f/3.f);
  }
}

// ---- fused pre-LN + LayerNorm ------------------------------------------------------
__global__ __launch_bounds__(256) void fuse_ln(
    const float* __restrict__ text, const float* __restrict__ att_t,
    const float* __restrict__ fcross, const float* __restrict__ lng,
    const float* __restrict__ lnb, bf16* __restrict__ shift){
  int row = blockIdx.x;
  int b = row/N, n = row - b*N;
  int tid=threadIdx.x;
  float v[3];
  for(int q=0;q<3;q++){
    int d=q*256+tid;
    int ch=(n*D+d)/50;
    v[q] = text[(size_t)row*D+d]*att_t[(size_t)b*D+ch] + fcross[(size_t)b*D+d];
  }
  __shared__ float red[256];
  red[tid]=v[0]+v[1]+v[2]; __syncthreads();
  for(int st=128;st>0;st>>=1){ if(tid<st) red[tid]+=red[tid+st]; __syncthreads(); }
  float m = red[0]*(1.f/768.f);
  __syncthreads();
  float s2=0.f;
  for(int q=0;q<3;q++){ float dl=v[q]-m; s2+=dl*dl; }
  red[tid]=s2; __syncthreads();
  for(int st=128;st>0;st>>=1){ if(tid<st) red[tid]+=red[tid+st]; __syncthreads(); }
  float var = red[0]*(1.f/768.f);
  float rs = 1.f/sqrtf(var+1e-5f);
  for(int q=0;q<3;q++){
    int d=q*256+tid;
    shift[(size_t)row*D+d]=__float2bfloat16((v[q]-m)*rs*lng[d]+lnb[d]);
  }
}

// ---- fused LSTM step: gates = [h|x]@[Whh|Wih]^T + b, one launch per timestep -------
// 1-D grid 768 blocks (3/CU), XCD-bijective swizzle: xcd = id&7 owns bx in [6*xcd,6*xcd+6)
// so its W slice (1.18 MB) + h/x (1.6 MB) stay L2-resident across re-reads and steps.
// Tile 32 m x 64 n'. BK=64, double-buffered LDS, ONE barrier per K-iter.
// Operand-swapped MFMA: acc[r] = gate r of one dg -> LSTM math in regs.
__global__ __launch_bounds__(256) void lstm_fused(
    const unsigned short* __restrict__ shift, const unsigned short* __restrict__ Wcat,
    const float* __restrict__ bsum, const unsigned short* __restrict__ hprev,
    unsigned short* __restrict__ hnext, float* __restrict__ cbuf,
    const float* __restrict__ text, const float* __restrict__ att_t,
    float* __restrict__ out, int t){
  __shared__ unsigned short Ab[2][64*40];    // [buf][kh*32+row][40]
  __shared__ unsigned short Bb[2][128*40];   // [buf][kh*64+row][40]
  const int tid=threadIdx.x;
  // ---- XCD-bijective decode: 8 XCDs x (6 bx panels x 16 by) ----
  const int id = blockIdx.x;
  const int xcd = id & 7;
  const int j = id >> 3;                 // 0..95 within XCD
  const int bx = xcd*6 + (j>>4);         // 0..47
  const int by = j & 15;                 // 0..15
  const int lane=tid&63, w=tid>>6, l15=lane&15, lq=lane>>4;

  // ---- staging maps (uint4 = 8 shorts per slot) ----
  const int sra = tid>>2, ca=(tid&3)*8;        // A: 64 subrows x 4 segs = 256 slots
  const int arow = sra&31, ah = sra>>5;
  const int dA = sra*40 + ca;
  const int b_a = by*32 + arow;
  const unsigned short* hThr = hprev + (size_t)b_a*D + ah*32 + ca;
  const unsigned short* xThr = shift + ((size_t)b_a*N + t)*D + ah*32 + ca;

  const int sr0 = tid>>2,        c0=(tid&3)*8;       // B slot 0: subrows 0..63 (kh=0)
  const int sr1 = (tid+256)>>2,  c1=(tid&3)*8;       // B slot 1: subrows 64..127 (kh=1)
  const int br0 = sr0&63, bh0 = sr0>>6;
  const int br1 = sr1&63, bh1 = sr1>>6;
  const unsigned short* bThr0 = Wcat + (size_t)(bx*64+br0)*KCAT + bh0*32 + c0;
  const unsigned short* bThr1 = Wcat + (size_t)(bx*64+br1)*KCAT + bh1*32 + c1;
  const int dB0 = sr0*40 + c0, dB1 = sr1*40 + c1;

  const int kbase  = t ? 0 : 768;              // t=0: h is zero -> skip Whh half
  const int nIters = t ? 24 : 12;

  floatx4 acc0={}, acc1={};

  // prologue: stage iter 0 into buf 0
  {
    const unsigned short* ap = (kbase<768) ? (hThr + kbase) : (xThr + (kbase-768));
    uint4 pA  = *(const uint4*)ap;
    uint4 pB0 = *(const uint4*)(bThr0 + kbase);
    uint4 pB1 = *(const uint4*)(bThr1 + kbase);
    *(uint4*)&Ab[0][dA]  = pA;
    *(uint4*)&Bb[0][dB0] = pB0;
    *(uint4*)&Bb[0][dB1] = pB1;
  }
  __syncthreads();

  #pragma unroll 2
  for(int it=0; it<nIters; ++it){
    const int cur = it&1;
    uint4 nA, nB0, nB1;
    const bool more = (it+1 < nIters);
    if(more){
      int kg = kbase + (it+1)*64;
      const unsigned short* ap = (kg<768) ? (hThr + kg) : (xThr + (kg-768));
      nA  = *(const uint4*)ap;
      nB0 = *(const uint4*)(bThr0 + kg);
      nB1 = *(const uint4*)(bThr1 + kg);
    }
    short8 Wf0 = *(const short8*)&Bb[cur][(w*16+l15)*40 + lq*8];
    short8 Wf1 = *(const short8*)&Bb[cur][(64 + w*16+l15)*40 + lq*8];
    short8 X00 = *(const short8*)&Ab[cur][(l15)*40 + lq*8];
    short8 X10 = *(const short8*)&Ab[cur][(16+l15)*40 + lq*8];
    short8 X01 = *(const short8*)&Ab[cur][(32+l15)*40 + lq*8];
    short8 X11 = *(const short8*)&Ab[cur][(48+l15)*40 + lq*8];
    acc0 = __builtin_amdgcn_mfma_f32_16x16x32_bf16(Wf0, X00, acc0, 0,0,0);
    acc1 = __builtin_amdgcn_mfma_f32_16x16x32_bf16(Wf0, X10, acc1, 0,0,0);
    acc0 = __builtin_amdgcn_mfma_f32_16x16x32_bf16(Wf1, X01, acc0, 0,0,0);
    acc1 = __builtin_amdgcn_mfma_f32_16x16x32_bf16(Wf1, X11, acc1, 0,0,0);
    if(more){
      *(uint4*)&Ab[cur^1][dA]  = nA;
      *(uint4*)&Bb[cur^1][dB0] = nB0;
      *(uint4*)&Bb[cur^1][dB1] = nB1;
    }
    __syncthreads();
  }

  // ---- epilogue: gates -> c,h ; fused residual out-write -----------------------
  const int nb = bx*64 + w*16 + lq*4;
  const int dg = nb>>2;                        // = bx*16 + w*4 + lq
  floatx4 bs = *(const floatx4*)&bsum[nb];
  #pragma unroll
  for(int mf=0; mf<2; ++mf){
    floatx4 a = mf ? acc1 : acc0;
    int b = by*32 + mf*16 + l15;
    float gi=a[0]+bs[0], gf=a[1]+bs[1], gg=a[2]+bs[2], go=a[3]+bs[3];
    float co = t ? cbuf[(size_t)b*D+dg] : 0.f;
    float cn = sigf(gf)*co + sigf(gi)*tanhf(gg);
    float hn = sigf(go)*tanhf(cn);
    cbuf[(size_t)b*D+dg] = cn;
    hnext[(size_t)b*D+dg] = f2u(hn);
    int ch = (t*D+dg)/50;
    size_t oi = ((size_t)b*N + t)*D + dg;
    out[oi] = hn + text[oi]*att_t[(size_t)b*D+ch];
  }
}

extern "C" void kernel_launch(void* const* d_in, const int* in_sizes, int n_in,
                              void* d_out, int out_size, void* d_ws, size_t ws_size,
                              hipStream_t stream){
  const float* text=(const float*)d_in[0];
  const int*  vid =(const int*) d_in[1];
  const int*  aid =(const int*) d_in[2];
  const float* vemb=(const float*)d_in[3];
  const float* aemb=(const float*)d_in[4];
  const float* egw =(const float*)d_in[5];
  const float* Wih =(const float*)d_in[6];
  const float* Whh =(const float*)d_in[7];
  const float* bih =(const float*)d_in[8];
  const float* bhh =(const float*)d_in[9];
  const float* lng =(const float*)d_in[10];
  const float* lnb =(const float*)d_in[11];
  const float* vW  =(const float*)d_in[20];
  const float* vb  =(const float*)d_in[21];
  float* out = (float*)d_out;

  // ---- workspace layout (~60 MB, under proven-safe 91 MB) ----
  float* W = (float*)d_ws;
  const size_t S = (size_t)B*D;
  float* att_t = W;
  float* fcross= att_t + S;
  float* cbuf  = fcross + S;
  float* bsum  = cbuf + S;               // G4
  float* fb    = bsum + G4;              // D
  unsigned short* Wcat = (unsigned short*)(fb + D);      // G4*KCAT
  unsigned short* WcB  = Wcat + (size_t)G4*KCAT;         // D*KC
  unsigned short* catAB= WcB + (size_t)D*KC;             // B*KC
  unsigned short* hA0  = catAB + (size_t)B*KC;           // S
  unsigned short* hA1  = hA0 + S;                        // S
  bf16*  shift = (bf16*)(hA1 + S);                       // BN*D

  prep_weights<<<G4,256,0,stream>>>(Wih,Whh,bih,bhh,Wcat,bsum);
  prep_fcross<<<D,256,0,stream>>>(vW,vb,WcB,fb);
  egce_fused<<<B,256,0,stream>>>(text,vid,aid,vemb,aemb,egw,att_t,catAB);
  fcross_mfma<<<dim3(12,16),256,0,stream>>>(catAB,WcB,fb,fcross);
  fuse_ln<<<BN,256,0,stream>>>(text,att_t,fcross,lng,lnb,shift);

  for(int t=0;t<N;t++){
    unsigned short* hp = (t&1)? hA1 : hA0;
    unsigned short* hn = (t&1)? hA0 : hA1;
    lstm_fused<<<768,256,0,stream>>>((const unsigned short*)shift,Wcat,bsum,
                                     hp,hn,cbuf,text,att_t,out,t);
  }
}